// Round 7
// baseline (233.600 us; speedup 1.0000x reference)
//
#include <hip/hip_runtime.h>
#include <cstdint>
#include <type_traits>

// ---------------- common types / helpers ----------------
typedef __attribute__((ext_vector_type(8))) short bf16x8;   // 8 bf16 in 4 VGPRs
typedef __attribute__((ext_vector_type(4))) float f32x4;

typedef unsigned int __attribute__((address_space(1))) as1_uint;
typedef unsigned int __attribute__((address_space(3))) as3_uint;

__device__ __forceinline__ void llds16(const void* g, void* l) {
  // async global->LDS, 16B per lane; LDS dst is wave-uniform base + lane*16
  __builtin_amdgcn_global_load_lds((const as1_uint*)g, (as3_uint*)l, 16, 0, 0);
}

__device__ __forceinline__ unsigned short f2bf(float f) {
  unsigned int u = __builtin_bit_cast(unsigned int, f);
  u = (u + 0x7fffu + ((u >> 16) & 1u)) >> 16;   // RNE
  return (unsigned short)u;
}
__device__ __forceinline__ float bf2f(unsigned short h) {
  unsigned int u = ((unsigned int)h) << 16;
  return __builtin_bit_cast(float, u);
}

// ---------------- elementwise convert f32 -> bf16 ----------------
__global__ __launch_bounds__(256) void cvt_f32_bf16(const float* __restrict__ in,
                                                    unsigned short* __restrict__ out, int n4) {
  int i = blockIdx.x * blockDim.x + threadIdx.x;
  int stride = gridDim.x * blockDim.x;
  for (; i < n4; i += stride) {
    float4 v = ((const float4*)in)[i];
    uint2 p;
    p.x = (unsigned)f2bf(v.x) | ((unsigned)f2bf(v.y) << 16);
    p.y = (unsigned)f2bf(v.z) | ((unsigned)f2bf(v.w) << 16);
    ((uint2*)out)[i] = p;
  }
}

// ---------------- transpose + convert: W[K][N] f32 -> Wt[N][K] bf16 ----------------
__global__ __launch_bounds__(256) void transpose_f32_bf16(const float* __restrict__ W,
                                                          unsigned short* __restrict__ Wt,
                                                          int K, int N) {
  __shared__ float tile[64][65];
  int n0 = blockIdx.x * 64, k0 = blockIdx.y * 64;
  int t = threadIdx.x;
  int lr = t >> 4, lc = (t & 15) * 4;
#pragma unroll
  for (int i = 0; i < 4; ++i) {
    int k = lr + i * 16;
    float4 v = *(const float4*)&W[(size_t)(k0 + k) * N + n0 + lc];
    tile[k][lc] = v.x; tile[k][lc + 1] = v.y; tile[k][lc + 2] = v.z; tile[k][lc + 3] = v.w;
  }
  __syncthreads();
  int n = t >> 2, kc = (t & 3) * 16;
  unsigned short* dst = &Wt[(size_t)(n0 + n) * K + k0 + kc];
#pragma unroll
  for (int j = 0; j < 16; ++j) dst[j] = f2bf(tile[kc + j][n]);
}

// ---------------- RoPE tables: cos/sin [T][32] ----------------
__global__ __launch_bounds__(256) void rope_tab(float* __restrict__ cosT, float* __restrict__ sinT) {
  int i = blockIdx.x * 256 + threadIdx.x;  // < 2048*32
  int t = i >> 5, j = i & 31;
  float inv = powf(10000.0f, -(float)j * (1.0f / 32.0f));
  float a = (float)t * inv;
  cosT[i] = cosf(a);
  sinT[i] = sinf(a);
}

// ---------------- NT GEMM: C[M][N] = A[M][K] * Bt[N][K]^T  (bf16 in, fp32 acc) ----------
template <typename OutT>
__global__ __launch_bounds__(256) void gemm_nt(const unsigned short* __restrict__ A,
                                               const unsigned short* __restrict__ Bt,
                                               OutT* __restrict__ C, int M, int N, int K) {
  __shared__ unsigned short As[128 * 32];
  __shared__ unsigned short Bs[128 * 32];
  const int tid = threadIdx.x;
  const int w = tid >> 6, lane = tid & 63;
  const int l15 = lane & 15, lg = lane >> 4;
  const int wr = w >> 1, wc = w & 1;
  const int m0 = blockIdx.y * 128, n0 = blockIdx.x * 128;

  f32x4 acc[4][4] = {};
  const int nk = K >> 5;
  for (int kt = 0; kt < nk; ++kt) {
    const int k0 = kt * 32;
    __syncthreads();
#pragma unroll
    for (int i = 0; i < 2; ++i) {
      int c = w + i * 4;                       // chunk 0..7, wave-uniform
      int o = c * 1024 + lane * 16;            // byte offset in 8KB tile
      int row = o >> 6, kb = o & 63;           // 64B per row (32 bf16)
      llds16((const char*)A + ((size_t)(m0 + row) * K + k0) * 2 + kb,
             (char*)As + c * 1024);
      llds16((const char*)Bt + ((size_t)(n0 + row) * K + k0) * 2 + kb,
             (char*)Bs + c * 1024);
    }
    __syncthreads();
    bf16x8 af[4], bfr[4];
#pragma unroll
    for (int m = 0; m < 4; ++m)
      af[m] = *(const bf16x8*)&As[(wr * 64 + m * 16 + l15) * 32 + lg * 8];
#pragma unroll
    for (int n = 0; n < 4; ++n)
      bfr[n] = *(const bf16x8*)&Bs[(wc * 64 + n * 16 + l15) * 32 + lg * 8];
#pragma unroll
    for (int m = 0; m < 4; ++m)
#pragma unroll
      for (int n = 0; n < 4; ++n)
        acc[m][n] = __builtin_amdgcn_mfma_f32_16x16x32_bf16(af[m], bfr[n], acc[m][n], 0, 0, 0);
  }
#pragma unroll
  for (int m = 0; m < 4; ++m)
#pragma unroll
    for (int n = 0; n < 4; ++n) {
      int row = m0 + wr * 64 + m * 16 + lg * 4;
      int col = n0 + wc * 64 + n * 16 + l15;
#pragma unroll
      for (int r = 0; r < 4; ++r) {
        if constexpr (std::is_same<OutT, float>::value)
          C[(size_t)(row + r) * N + col] = acc[m][n][r];
        else
          C[(size_t)(row + r) * N + col] = f2bf(acc[m][n][r]);
      }
    }
}

// ---------------- per-head RMSNorm + RoPE + relayout (Q,K only) ----------------
// qkv bf16 [B*T][3C] -> Qr/Kr bf16 [B*H][T][64]
// Q pre-scaled by log2(e)/8 so attention softmax is a bare exp2.
__global__ __launch_bounds__(256) void qkv_post(const unsigned short* __restrict__ qkv,
                                                const float* __restrict__ qw,
                                                const float* __restrict__ kw,
                                                const float* __restrict__ cosT,
                                                const float* __restrict__ sinT,
                                                unsigned short* __restrict__ Qr,
                                                unsigned short* __restrict__ Kr) {
  int bt = blockIdx.x;
  int b = bt >> 11, t = bt & 2047;
  int tid = threadIdx.x, h = tid >> 4, g = tid & 15, d0 = g * 4;
  const unsigned short* base = qkv + (size_t)bt * 3072;
  int dm = d0 & 31;
  float4 cv = *(const float4*)&cosT[t * 32 + dm];
  float4 sv = *(const float4*)&sinT[t * 32 + dm];
  float sgn = (g < 8) ? -1.0f : 1.0f;
  size_t oofs = (((size_t)(b * 16 + h)) * 2048 + t) * 64 + d0;

#pragma unroll
  for (int s = 0; s < 2; ++s) {
    const float* wt = s ? kw : qw;
    float scale = s ? 1.0f : 0.18033688011112042f;   // log2(e)/8
    unsigned short* outp = s ? Kr : Qr;
    ushort4 raw = *(const ushort4*)(base + s * 1024 + h * 64 + d0);
    float x0 = bf2f(raw.x), x1 = bf2f(raw.y), x2 = bf2f(raw.z), x3 = bf2f(raw.w);
    float ssq = x0 * x0 + x1 * x1 + x2 * x2 + x3 * x3;
    ssq += __shfl_xor(ssq, 1); ssq += __shfl_xor(ssq, 2);
    ssq += __shfl_xor(ssq, 4); ssq += __shfl_xor(ssq, 8);
    float f = rsqrtf(ssq * (1.0f / 64.0f) + 1e-5f);
    float4 w4 = *(const float4*)&wt[d0];
    float n0 = x0 * f * w4.x, n1 = x1 * f * w4.y, n2 = x2 * f * w4.z, n3 = x3 * f * w4.w;
    float p0 = __shfl_xor(n0, 8), p1 = __shfl_xor(n1, 8), p2 = __shfl_xor(n2, 8), p3 = __shfl_xor(n3, 8);
    float o0 = (n0 * cv.x + sgn * p0 * sv.x) * scale;
    float o1 = (n1 * cv.y + sgn * p1 * sv.y) * scale;
    float o2 = (n2 * cv.z + sgn * p2 * sv.z) * scale;
    float o3 = (n3 * cv.w + sgn * p3 * sv.w) * scale;
    uint2 pk;
    pk.x = (unsigned)f2bf(o0) | ((unsigned)f2bf(o1) << 16);
    pk.y = (unsigned)f2bf(o2) | ((unsigned)f2bf(o3) << 16);
    *(uint2*)(outp + oofs) = pk;
  }
}

// ---------------- V transpose: qkv V-part [B*T][...] -> Vtg [B*H][64 d][2048 t] -------
__global__ __launch_bounds__(256) void vtrans(const unsigned short* __restrict__ qkv,
                                              unsigned short* __restrict__ Vtg) {
  __shared__ unsigned short tile[64][72];
  int bh = blockIdx.y, b = bh >> 4, h = bh & 15;
  int t0 = blockIdx.x * 64;
  int tid = threadIdx.x;
  int r = tid >> 2, c0 = (tid & 3) * 16;
  const unsigned short* src = qkv + (size_t)(b * 2048 + t0 + r) * 3072 + 2048 + h * 64 + c0;
  *(bf16x8*)&tile[r][c0] = *(const bf16x8*)src;
  *(bf16x8*)&tile[r][c0 + 8] = *(const bf16x8*)(src + 8);
  __syncthreads();
  int d = tid >> 2, t4 = (tid & 3) * 16;
  unsigned short* dst = &Vtg[((size_t)bh * 64 + d) * 2048 + t0 + t4];
  unsigned short pack[16];
#pragma unroll
  for (int j = 0; j < 16; ++j) pack[j] = tile[t4 + j][d];
  *(bf16x8*)dst = *(bf16x8*)&pack[0];
  *(bf16x8*)(dst + 8) = *(bf16x8*)&pack[8];
}

// ---------------- causal flash attention: swapped operands, reg-staged async ----------
// Q,K: [B*H][T][64] bf16 (Q pre-scaled by log2e/8). Vtg: [B*H][64][T] bf16.
// Y: [B][T][H*64] bf16.
// T14 async staging: issue 4 global_load_dwordx4 -> VGPRs for tile kt+1 at the
// START of tile kt (HBM latency hides under compute), ds_write to swizzled LDS
// AFTER compute, barrier only orders LDS writes (not HBM).
// Swapped-operand MFMA: mfma(Kfrag,Qfrag)->S^T, mfma(Vtfrag,Pfrag)->O^T; each
// lane owns one q column -> scalar psum, packed P stores, vector Y stores.
// QBLK=64 (4 waves x 16 q), KVBLK=64, paired q-tiles {31-p, p} -> uniform load.
// |q.k|/8 <= 8 (RMSNormed rows, RoPE rotation) -> fixed-max softmax p=exp2(s).
__global__ __launch_bounds__(256) void attn_fwd(const unsigned short* __restrict__ Q,
                                                const unsigned short* __restrict__ K,
                                                const unsigned short* __restrict__ Vtg,
                                                unsigned short* __restrict__ Y) {
  const int bh = blockIdx.x;        // 0..63
  const int pr = blockIdx.y;        // 0..15
  const int b = bh >> 4, h = bh & 15;
  const int tid = threadIdx.x;
  const int w = tid >> 6, lane = tid & 63;
  const int l15 = lane & 15, lg = lane >> 4;

  __shared__ unsigned short Kl[2][64 * 64];   // swizzled [k][d], 128B rows (16384 B)
  __shared__ unsigned short Vt[2][64 * 64];   // swizzled [d][k], 128B rows (16384 B)
  __shared__ unsigned short Pl[4][16 * 64];   // per-wave P^T [q][k], 128B rows, swz (8192 B)

  const size_t bhT = (size_t)bh * 2048;
  const char* Kg = (const char*)(K + bhT * 64);          // row stride 128B
  const char* Vg = (const char*)(Vtg + bhT * 64);        // row stride 4096B

  // per-lane staging geometry (all loop-invariant)
  const int pos0 = w * 2048 + lane * 16;       // bytes in 8KB tile, chunk 0
  const int pos1 = pos0 + 1024;                // chunk 1
  const int r0 = pos0 >> 7, c0 = pos0 & 127;
  const int r1 = pos1 >> 7, c1 = pos1 & 127;
  const int kOff0 = r0 * 128 + c0, kOff1 = r1 * 128 + c1;        // K global byte offs
  const int vOff0 = r0 * 4096 + c0, vOff1 = r1 * 4096 + c1;      // V global byte offs
  const int dst0 = r0 * 128 + (c0 ^ ((r0 & 7) << 4));            // swizzled LDS dst
  const int dst1 = r1 * 128 + (c1 ^ ((r1 & 7) << 4));

  uint4 skr0, skr1, svr0, svr1;    // in-flight staging registers

  auto stage_load = [&](int kt) {
    const char* kb = Kg + (size_t)kt * 8192;
    const char* vb = Vg + (size_t)kt * 128;
    skr0 = *(const uint4*)(kb + kOff0);
    skr1 = *(const uint4*)(kb + kOff1);
    svr0 = *(const uint4*)(vb + vOff0);
    svr1 = *(const uint4*)(vb + vOff1);
  };
  auto stage_write = [&](int buf) {
    char* kd = (char*)&Kl[buf][0];
    char* vd = (char*)&Vt[buf][0];
    *(uint4*)(kd + dst0) = skr0;
    *(uint4*)(kd + dst1) = skr1;
    *(uint4*)(vd + dst0) = svr0;
    *(uint4*)(vd + dst1) = svr1;
  };

  auto run_qtile = [&](int qtb) {
    const int qbase = qtb * 64;
    const unsigned short* Qp = Q + (bhT + qbase + w * 16 + l15) * 64 + lg * 8;
    bf16x8 aq[2];
    aq[0] = *(const bf16x8*)(Qp);
    aq[1] = *(const bf16x8*)(Qp + 32);

    f32x4 o[4] = {};        // O^T: lane q=l15, rows d = df*16 + lg*4 + r
    float psum = 0.0f;      // per-lane (q = l15) partial sum over its k slice

    char* Pw = (char*)&Pl[w][0];
    const int psw = (l15 & 7) << 4;       // 16B-granular XOR swizzle keyed by q-row

    for (int kt = 0; kt <= qtb; ++kt) {
      const int cur = kt & 1;
      if (kt < qtb) stage_load(kt + 1);   // issue early: latency hides under compute
      const char* Kc = (const char*)&Kl[cur][0];
      const char* Vc = (const char*)&Vt[cur][0];

      f32x4 s[4] = {};      // S^T: lane q=l15, rows k = n*16 + lg*4 + r
      __builtin_amdgcn_s_setprio(1);
#pragma unroll
      for (int n = 0; n < 4; ++n) {
        int r = n * 16 + l15, sw = (r & 7) << 4;
#pragma unroll
        for (int ks = 0; ks < 2; ++ks) {
          bf16x8 bk = *(const bf16x8*)(Kc + r * 128 + ((ks * 64 + lg * 16) ^ sw));
          s[n] = __builtin_amdgcn_mfma_f32_16x16x32_bf16(bk, aq[ks], s[n], 0, 0, 0);
        }
      }
      __builtin_amdgcn_s_setprio(0);

      if (kt == qtb) {   // diagonal tile: causal mask (k_local > q_local)
#pragma unroll
        for (int n = 0; n < 4; ++n)
#pragma unroll
          for (int r = 0; r < 4; ++r)
            if (n * 16 + lg * 4 + r > w * 16 + l15) s[n][r] = -1e30f;
      }

      // p = exp2(s); per-lane psum; pack 4 k-contiguous bf16 -> one b64 LDS write
#pragma unroll
      for (int n = 0; n < 4; ++n) {
        float p0 = __builtin_exp2f(s[n][0]);
        float p1 = __builtin_exp2f(s[n][1]);
        float p2 = __builtin_exp2f(s[n][2]);
        float p3 = __builtin_exp2f(s[n][3]);
        psum += (p0 + p1) + (p2 + p3);
        uint2 pk;
        pk.x = ((__builtin_bit_cast(unsigned int, p0) + 0x8000u) >> 16) |
               (((__builtin_bit_cast(unsigned int, p1) + 0x8000u) >> 16) << 16);
        pk.y = ((__builtin_bit_cast(unsigned int, p2) + 0x8000u) >> 16) |
               (((__builtin_bit_cast(unsigned int, p3) + 0x8000u) >> 16) << 16);
        *(uint2*)(Pw + l15 * 128 + ((n * 32 + lg * 8) ^ psw)) = pk;
      }
      asm volatile("" ::: "memory");  // keep P stores before P reads (per-wave LDS in-order)

      bf16x8 ap[2];
      ap[0] = *(const bf16x8*)(Pw + l15 * 128 + ((lg * 16) ^ psw));
      ap[1] = *(const bf16x8*)(Pw + l15 * 128 + ((64 + lg * 16) ^ psw));

      __builtin_amdgcn_s_setprio(1);
#pragma unroll
      for (int df = 0; df < 4; ++df) {
        int rr = df * 16 + l15, sw = (rr & 7) << 4;
#pragma unroll
        for (int ks = 0; ks < 2; ++ks) {
          bf16x8 bv = *(const bf16x8*)(Vc + rr * 128 + ((ks * 64 + lg * 16) ^ sw));
          o[df] = __builtin_amdgcn_mfma_f32_16x16x32_bf16(bv, ap[ks], o[df], 0, 0, 0);
        }
      }
      __builtin_amdgcn_s_setprio(0);

      if (kt < qtb) stage_write(cur ^ 1);  // vmcnt waits only this wave's 4 loads
      __syncthreads();                     // orders LDS writes only (no HBM drain)
    }

    // full row-sum: combine the 4 lanes sharing this q (lg differs in bits 4..5)
    psum += __shfl_xor(psum, 16);
    psum += __shfl_xor(psum, 32);
    float inv = 1.0f / psum;

    size_t q = qbase + w * 16 + l15;
    unsigned short* yp = Y + ((size_t)b * 2048 + q) * 1024 + h * 64 + lg * 4;
#pragma unroll
    for (int df = 0; df < 4; ++df) {
      ushort4 v;
      v.x = f2bf(o[df][0] * inv);
      v.y = f2bf(o[df][1] * inv);
      v.z = f2bf(o[df][2] * inv);
      v.w = f2bf(o[df][3] * inv);
      *(ushort4*)(yp + df * 16) = v;
    }
  };

  // heavy segment then light segment; every block: 33 kv-tile iterations total
  stage_load(0);
  stage_write(0);
  __syncthreads();
  run_qtile(31 - pr);
  stage_load(0);
  stage_write(0);
  __syncthreads();
  run_qtile(pr);
}

// ---------------- launch ----------------
extern "C" void kernel_launch(void* const* d_in, const int* in_sizes, int n_in,
                              void* d_out, int out_size, void* d_ws, size_t ws_size,
                              hipStream_t stream) {
  const float* x = (const float*)d_in[0];
  const float* Wqkv = (const float*)d_in[1];
  const float* Wproj = (const float*)d_in[2];
  const float* qw = (const float*)d_in[3];
  const float* kw = (const float*)d_in[4];
  float* out = (float*)d_out;

  char* ws = (char*)d_ws;
  unsigned short* xb = (unsigned short*)ws;        ws += (size_t)8192 * 1024 * 2;
  unsigned short* wqkvt = (unsigned short*)ws;     ws += (size_t)3072 * 1024 * 2;
  unsigned short* wprojt = (unsigned short*)ws;    ws += (size_t)1024 * 1024 * 2;
  unsigned short* qkvb = (unsigned short*)ws;      ws += (size_t)8192 * 3072 * 2;
  unsigned short* Qr = (unsigned short*)ws;        ws += (size_t)64 * 2048 * 64 * 2;
  unsigned short* Kr = (unsigned short*)ws;        ws += (size_t)64 * 2048 * 64 * 2;
  unsigned short* Vtg = (unsigned short*)ws;       ws += (size_t)64 * 64 * 2048 * 2;
  unsigned short* yb = (unsigned short*)ws;        ws += (size_t)8192 * 1024 * 2;
  float* cosT = (float*)ws;                        ws += (size_t)2048 * 32 * 4;
  float* sinT = (float*)ws;                        ws += (size_t)2048 * 32 * 4;

  cvt_f32_bf16<<<2048, 256, 0, stream>>>(x, xb, 8192 * 1024 / 4);
  transpose_f32_bf16<<<dim3(48, 16), 256, 0, stream>>>(Wqkv, wqkvt, 1024, 3072);
  transpose_f32_bf16<<<dim3(16, 16), 256, 0, stream>>>(Wproj, wprojt, 1024, 1024);
  rope_tab<<<256, 256, 0, stream>>>(cosT, sinT);
  gemm_nt<unsigned short><<<dim3(24, 64), 256, 0, stream>>>(xb, wqkvt, qkvb, 8192, 3072, 1024);
  qkv_post<<<8192, 256, 0, stream>>>(qkvb, qw, kw, cosT, sinT, Qr, Kr);
  vtrans<<<dim3(32, 64), 256, 0, stream>>>(qkvb, Vtg);
  attn_fwd<<<dim3(64, 16), 256, 0, stream>>>(Qr, Kr, Vtg, yb);
  gemm_nt<float><<<dim3(8, 64), 256, 0, stream>>>(yb, wprojt, out, 8192, 1024, 1024);
}

// Round 8
// 208.853 us; speedup vs baseline: 1.1185x; 1.1185x over previous
//
#include <hip/hip_runtime.h>
#include <cstdint>
#include <type_traits>

// ---------------- common types / helpers ----------------
typedef __attribute__((ext_vector_type(8))) short bf16x8;   // 8 bf16 in 4 VGPRs
typedef __attribute__((ext_vector_type(4))) float f32x4;

typedef unsigned int __attribute__((address_space(1))) as1_uint;
typedef unsigned int __attribute__((address_space(3))) as3_uint;

__device__ __forceinline__ void llds16(const void* g, void* l) {
  // async global->LDS, 16B per lane; LDS dst is wave-uniform base + lane*16
  __builtin_amdgcn_global_load_lds((const as1_uint*)g, (as3_uint*)l, 16, 0, 0);
}

__device__ __forceinline__ unsigned short f2bf(float f) {
  unsigned int u = __builtin_bit_cast(unsigned int, f);
  u = (u + 0x7fffu + ((u >> 16) & 1u)) >> 16;   // RNE
  return (unsigned short)u;
}
__device__ __forceinline__ float bf2f(unsigned short h) {
  unsigned int u = ((unsigned int)h) << 16;
  return __builtin_bit_cast(float, u);
}

// ---------------- elementwise convert f32 -> bf16 ----------------
__global__ __launch_bounds__(256) void cvt_f32_bf16(const float* __restrict__ in,
                                                    unsigned short* __restrict__ out, int n4) {
  int i = blockIdx.x * blockDim.x + threadIdx.x;
  int stride = gridDim.x * blockDim.x;
  for (; i < n4; i += stride) {
    float4 v = ((const float4*)in)[i];
    uint2 p;
    p.x = (unsigned)f2bf(v.x) | ((unsigned)f2bf(v.y) << 16);
    p.y = (unsigned)f2bf(v.z) | ((unsigned)f2bf(v.w) << 16);
    ((uint2*)out)[i] = p;
  }
}

// ---------------- transpose + convert: W[K][N] f32 -> Wt[N][K] bf16 ----------------
__global__ __launch_bounds__(256) void transpose_f32_bf16(const float* __restrict__ W,
                                                          unsigned short* __restrict__ Wt,
                                                          int K, int N) {
  __shared__ float tile[64][65];
  int n0 = blockIdx.x * 64, k0 = blockIdx.y * 64;
  int t = threadIdx.x;
  int lr = t >> 4, lc = (t & 15) * 4;
#pragma unroll
  for (int i = 0; i < 4; ++i) {
    int k = lr + i * 16;
    float4 v = *(const float4*)&W[(size_t)(k0 + k) * N + n0 + lc];
    tile[k][lc] = v.x; tile[k][lc + 1] = v.y; tile[k][lc + 2] = v.z; tile[k][lc + 3] = v.w;
  }
  __syncthreads();
  int n = t >> 2, kc = (t & 3) * 16;
  unsigned short* dst = &Wt[(size_t)(n0 + n) * K + k0 + kc];
#pragma unroll
  for (int j = 0; j < 16; ++j) dst[j] = f2bf(tile[kc + j][n]);
}

// ---------------- RoPE tables: cos/sin [T][32] ----------------
__global__ __launch_bounds__(256) void rope_tab(float* __restrict__ cosT, float* __restrict__ sinT) {
  int i = blockIdx.x * 256 + threadIdx.x;  // < 2048*32
  int t = i >> 5, j = i & 31;
  float inv = powf(10000.0f, -(float)j * (1.0f / 32.0f));
  float a = (float)t * inv;
  cosT[i] = cosf(a);
  sinT[i] = sinf(a);
}

// ---------------- ring-3 NT GEMM: C[M][N] = A[M][K] * Bt[N][K]^T ----------------------
// 128x128 tile, BK=32, 4 waves 2x2. THREE LDS buffer sets (48 KB -> 3 blocks/CU).
// Stage K-tile t+2 while computing tile t: per-iter wait is vmcnt(4) for loads
// issued TWO iterations ago (never a drain) + raw s_barrier (no compiler vmcnt(0)).
// LDS XOR-swizzled: byte_col ^= ((row>>1)&3)<<4 -> 8 distinct bank-starts (2-way, free);
// staged via global_load_lds with inverse-swizzled global source (both-sides rule).
// XCD-chunked block swizzle (requires nwg % 8 == 0).
template <typename OutT>
__global__ __launch_bounds__(256) void gemm_ring(const unsigned short* __restrict__ A,
                                                 const unsigned short* __restrict__ Bt,
                                                 OutT* __restrict__ C, int M, int N, int K) {
  __shared__ unsigned short As[3][128 * 32];
  __shared__ unsigned short Bs[3][128 * 32];
  const int tid = threadIdx.x;
  const int w = tid >> 6, lane = tid & 63;
  const int l15 = lane & 15, lg = lane >> 4;
  const int wr = w >> 1, wc = w & 1;

  // XCD-chunked swizzle (bijective since nwg % 8 == 0)
  const int nwg = gridDim.x * gridDim.y;
  const int lin = blockIdx.y * gridDim.x + blockIdx.x;
  const int swzb = (lin & 7) * (nwg >> 3) + (lin >> 3);
  const int bx = swzb % gridDim.x, by = swzb / gridDim.x;
  const int m0 = by * 128, n0 = bx * 128;

  const size_t K2 = (size_t)K * 2;
  const char* Ag = (const char*)A;
  const char* Bg = (const char*)Bt;

  // staging geometry: chunk c (1024B) covers rows c*16..c*16+15 (64B rows)
  const int rc = lane >> 2;            // row within chunk 0..15
  const int cb = (lane & 3) * 16;      // byte col within row

  auto stage = [&](int buf, int kt) {
#pragma unroll
    for (int i = 0; i < 2; ++i) {
      int c = w + i * 4;               // chunk 0..7, wave-uniform
      int row = c * 16 + rc;
      int srcc = cb ^ (((row >> 1) & 3) << 4);   // inverse-swizzled source col
      size_t kofs = (size_t)kt * 64 + srcc;
      llds16(Ag + (size_t)(m0 + row) * K2 + kofs, (char*)&As[buf][0] + c * 1024);
      llds16(Bg + (size_t)(n0 + row) * K2 + kofs, (char*)&Bs[buf][0] + c * 1024);
    }
  };

  f32x4 acc[4][4] = {};
  const int nk = K >> 5;

  stage(0, 0);
  stage(1, 1);

  int cur = 0;
  for (int t = 0; t < nk; ++t) {
    asm volatile("s_waitcnt vmcnt(4)" ::: "memory");  // tile t resident (issued 2 iters ago)
    __builtin_amdgcn_s_barrier();
    asm volatile("" ::: "memory");
    if (t + 2 < nk) stage(cur + 2 >= 3 ? cur - 1 : cur + 2, t + 2);

    const unsigned short* Ab = &As[cur][0];
    const unsigned short* Bb = &Bs[cur][0];
    bf16x8 af[4], bfr[4];
#pragma unroll
    for (int m = 0; m < 4; ++m) {
      int row = wr * 64 + m * 16 + l15;
      af[m] = *(const bf16x8*)((const char*)Ab + row * 64 + ((lg * 16) ^ (((row >> 1) & 3) << 4)));
    }
#pragma unroll
    for (int n = 0; n < 4; ++n) {
      int row = wc * 64 + n * 16 + l15;
      bfr[n] = *(const bf16x8*)((const char*)Bb + row * 64 + ((lg * 16) ^ (((row >> 1) & 3) << 4)));
    }
#pragma unroll
    for (int m = 0; m < 4; ++m)
#pragma unroll
      for (int n = 0; n < 4; ++n)
        acc[m][n] = __builtin_amdgcn_mfma_f32_16x16x32_bf16(af[m], bfr[n], acc[m][n], 0, 0, 0);

    cur = (cur == 2) ? 0 : cur + 1;
  }

#pragma unroll
  for (int m = 0; m < 4; ++m)
#pragma unroll
    for (int n = 0; n < 4; ++n) {
      int row = m0 + wr * 64 + m * 16 + lg * 4;
      int col = n0 + wc * 64 + n * 16 + l15;
#pragma unroll
      for (int r = 0; r < 4; ++r) {
        if constexpr (std::is_same<OutT, float>::value)
          C[(size_t)(row + r) * N + col] = acc[m][n][r];
        else
          C[(size_t)(row + r) * N + col] = f2bf(acc[m][n][r]);
      }
    }
}

// ---------------- per-head RMSNorm + RoPE + relayout (Q,K only) ----------------
// qkv bf16 [B*T][3C] -> Qr/Kr bf16 [B*H][T][64]
// Q pre-scaled by log2(e)/8 so attention softmax is a bare exp2.
__global__ __launch_bounds__(256) void qkv_post(const unsigned short* __restrict__ qkv,
                                                const float* __restrict__ qw,
                                                const float* __restrict__ kw,
                                                const float* __restrict__ cosT,
                                                const float* __restrict__ sinT,
                                                unsigned short* __restrict__ Qr,
                                                unsigned short* __restrict__ Kr) {
  int bt = blockIdx.x;
  int b = bt >> 11, t = bt & 2047;
  int tid = threadIdx.x, h = tid >> 4, g = tid & 15, d0 = g * 4;
  const unsigned short* base = qkv + (size_t)bt * 3072;
  int dm = d0 & 31;
  float4 cv = *(const float4*)&cosT[t * 32 + dm];
  float4 sv = *(const float4*)&sinT[t * 32 + dm];
  float sgn = (g < 8) ? -1.0f : 1.0f;
  size_t oofs = (((size_t)(b * 16 + h)) * 2048 + t) * 64 + d0;

#pragma unroll
  for (int s = 0; s < 2; ++s) {
    const float* wt = s ? kw : qw;
    float scale = s ? 1.0f : 0.18033688011112042f;   // log2(e)/8
    unsigned short* outp = s ? Kr : Qr;
    ushort4 raw = *(const ushort4*)(base + s * 1024 + h * 64 + d0);
    float x0 = bf2f(raw.x), x1 = bf2f(raw.y), x2 = bf2f(raw.z), x3 = bf2f(raw.w);
    float ssq = x0 * x0 + x1 * x1 + x2 * x2 + x3 * x3;
    ssq += __shfl_xor(ssq, 1); ssq += __shfl_xor(ssq, 2);
    ssq += __shfl_xor(ssq, 4); ssq += __shfl_xor(ssq, 8);
    float f = rsqrtf(ssq * (1.0f / 64.0f) + 1e-5f);
    float4 w4 = *(const float4*)&wt[d0];
    float n0 = x0 * f * w4.x, n1 = x1 * f * w4.y, n2 = x2 * f * w4.z, n3 = x3 * f * w4.w;
    float p0 = __shfl_xor(n0, 8), p1 = __shfl_xor(n1, 8), p2 = __shfl_xor(n2, 8), p3 = __shfl_xor(n3, 8);
    float o0 = (n0 * cv.x + sgn * p0 * sv.x) * scale;
    float o1 = (n1 * cv.y + sgn * p1 * sv.y) * scale;
    float o2 = (n2 * cv.z + sgn * p2 * sv.z) * scale;
    float o3 = (n3 * cv.w + sgn * p3 * sv.w) * scale;
    uint2 pk;
    pk.x = (unsigned)f2bf(o0) | ((unsigned)f2bf(o1) << 16);
    pk.y = (unsigned)f2bf(o2) | ((unsigned)f2bf(o3) << 16);
    *(uint2*)(outp + oofs) = pk;
  }
}

// ---------------- V transpose: qkv V-part [B*T][...] -> Vtg [B*H][64 d][2048 t] -------
__global__ __launch_bounds__(256) void vtrans(const unsigned short* __restrict__ qkv,
                                              unsigned short* __restrict__ Vtg) {
  __shared__ unsigned short tile[64][72];
  int bh = blockIdx.y, b = bh >> 4, h = bh & 15;
  int t0 = blockIdx.x * 64;
  int tid = threadIdx.x;
  int r = tid >> 2, c0 = (tid & 3) * 16;
  const unsigned short* src = qkv + (size_t)(b * 2048 + t0 + r) * 3072 + 2048 + h * 64 + c0;
  *(bf16x8*)&tile[r][c0] = *(const bf16x8*)src;
  *(bf16x8*)&tile[r][c0 + 8] = *(const bf16x8*)(src + 8);
  __syncthreads();
  int d = tid >> 2, t4 = (tid & 3) * 16;
  unsigned short* dst = &Vtg[((size_t)bh * 64 + d) * 2048 + t0 + t4];
  unsigned short pack[16];
#pragma unroll
  for (int j = 0; j < 16; ++j) pack[j] = tile[t4 + j][d];
  *(bf16x8*)dst = *(bf16x8*)&pack[0];
  *(bf16x8*)(dst + 8) = *(bf16x8*)&pack[8];
}

// ---------------- causal flash attention: swapped operands, fixed-max softmax ----------
// (R6 version, measured 86.7 us) Q,K: [B*H][T][64] bf16 (Q pre-scaled by log2e/8).
// Vtg: [B*H][64][T] bf16. Y: [B][T][H*64] bf16.
// Swapped-operand trick: mfma(Kfrag, Qfrag) -> S^T, mfma(Vtfrag, Pfrag) -> O^T.
// Each lane owns one q column: scalar psum, packed P stores, vector Y stores.
// QBLK=64 (4 waves x 16 q), KVBLK=64, paired q-tiles {31-p, p} -> uniform load.
__global__ __launch_bounds__(256) void attn_fwd(const unsigned short* __restrict__ Q,
                                                const unsigned short* __restrict__ K,
                                                const unsigned short* __restrict__ Vtg,
                                                unsigned short* __restrict__ Y) {
  const int bh = blockIdx.x;        // 0..63
  const int pr = blockIdx.y;        // 0..15
  const int b = bh >> 4, h = bh & 15;
  const int tid = threadIdx.x;
  const int w = tid >> 6, lane = tid & 63;
  const int l15 = lane & 15, lg = lane >> 4;

  __shared__ unsigned short Kl[2][64 * 64];   // swizzled [k][d], 128B rows (16384 B)
  __shared__ unsigned short Vt[2][64 * 64];   // swizzled [d][k], 128B rows (16384 B)
  __shared__ unsigned short Pl[4][16 * 64];   // per-wave P^T [q][k], 128B rows, swz (8192 B)

  const size_t bhT = (size_t)bh * 2048;
  const char* Kg = (const char*)(K + bhT * 64);          // row stride 128B
  const char* Vg = (const char*)(Vtg + bhT * 64);        // row stride 4096B

  auto stage = [&](int buf, int kt) {
#pragma unroll
    for (int i = 0; i < 2; ++i) {
      int c = w * 2 + i;                     // chunk 0..7, wave-uniform
      int pos = c * 1024 + lane * 16;        // linear byte in 8KB tile
      int row = pos >> 7, cb = pos & 127;
      int srcb = cb ^ ((row & 7) << 4);      // inverse-swizzled source
      llds16(Kg + ((size_t)(kt * 64 + row)) * 128 + srcb,
             (char*)&Kl[buf][0] + c * 1024);
      llds16(Vg + (size_t)row * 4096 + (size_t)kt * 128 + srcb,
             (char*)&Vt[buf][0] + c * 1024);
    }
  };

  auto run_qtile = [&](int qtb) {
    const int qbase = qtb * 64;
    const unsigned short* Qp = Q + (bhT + qbase + w * 16 + l15) * 64 + lg * 8;
    bf16x8 aq[2];
    aq[0] = *(const bf16x8*)(Qp);
    aq[1] = *(const bf16x8*)(Qp + 32);

    f32x4 o[4] = {};        // O^T: lane q=l15, rows d = df*16 + lg*4 + r
    float psum = 0.0f;      // per-lane (q = l15) partial sum over its k slice

    char* Pw = (char*)&Pl[w][0];
    const int psw = (l15 & 7) << 4;       // 16B-granular XOR swizzle keyed by q-row

    for (int kt = 0; kt <= qtb; ++kt) {
      const int cur = kt & 1;
      if (kt < qtb) stage(cur ^ 1, kt + 1);
      const char* Kc = (const char*)&Kl[cur][0];
      const char* Vc = (const char*)&Vt[cur][0];

      f32x4 s[4] = {};      // S^T: lane q=l15, rows k = n*16 + lg*4 + r
      __builtin_amdgcn_s_setprio(1);
#pragma unroll
      for (int n = 0; n < 4; ++n) {
        int r = n * 16 + l15, sw = (r & 7) << 4;
#pragma unroll
        for (int ks = 0; ks < 2; ++ks) {
          bf16x8 bk = *(const bf16x8*)(Kc + r * 128 + ((ks * 64 + lg * 16) ^ sw));
          s[n] = __builtin_amdgcn_mfma_f32_16x16x32_bf16(bk, aq[ks], s[n], 0, 0, 0);
        }
      }
      __builtin_amdgcn_s_setprio(0);

      if (kt == qtb) {   // diagonal tile: causal mask (k_local > q_local)
#pragma unroll
        for (int n = 0; n < 4; ++n)
#pragma unroll
          for (int r = 0; r < 4; ++r)
            if (n * 16 + lg * 4 + r > w * 16 + l15) s[n][r] = -1e30f;
      }

      // p = exp2(s); per-lane psum; pack 4 k-contiguous bf16 -> one b64 LDS write
#pragma unroll
      for (int n = 0; n < 4; ++n) {
        float p0 = __builtin_exp2f(s[n][0]);
        float p1 = __builtin_exp2f(s[n][1]);
        float p2 = __builtin_exp2f(s[n][2]);
        float p3 = __builtin_exp2f(s[n][3]);
        psum += (p0 + p1) + (p2 + p3);
        uint2 pk;
        pk.x = ((__builtin_bit_cast(unsigned int, p0) + 0x8000u) >> 16) |
               (((__builtin_bit_cast(unsigned int, p1) + 0x8000u) >> 16) << 16);
        pk.y = ((__builtin_bit_cast(unsigned int, p2) + 0x8000u) >> 16) |
               (((__builtin_bit_cast(unsigned int, p3) + 0x8000u) >> 16) << 16);
        *(uint2*)(Pw + l15 * 128 + ((n * 32 + lg * 8) ^ psw)) = pk;
      }
      asm volatile("" ::: "memory");  // keep P stores before P reads (per-wave LDS in-order)

      bf16x8 ap[2];
      ap[0] = *(const bf16x8*)(Pw + l15 * 128 + ((lg * 16) ^ psw));
      ap[1] = *(const bf16x8*)(Pw + l15 * 128 + ((64 + lg * 16) ^ psw));

      __builtin_amdgcn_s_setprio(1);
#pragma unroll
      for (int df = 0; df < 4; ++df) {
        int rr = df * 16 + l15, sw = (rr & 7) << 4;
#pragma unroll
        for (int ks = 0; ks < 2; ++ks) {
          bf16x8 bv = *(const bf16x8*)(Vc + rr * 128 + ((ks * 64 + lg * 16) ^ sw));
          o[df] = __builtin_amdgcn_mfma_f32_16x16x32_bf16(bv, ap[ks], o[df], 0, 0, 0);
        }
      }
      __builtin_amdgcn_s_setprio(0);
      __syncthreads();  // drains next-tile staging; protects cur from overwrite
    }

    // full row-sum: combine the 4 lanes sharing this q (lg differs in bits 4..5)
    psum += __shfl_xor(psum, 16);
    psum += __shfl_xor(psum, 32);
    float inv = 1.0f / psum;

    size_t q = qbase + w * 16 + l15;
    unsigned short* yp = Y + ((size_t)b * 2048 + q) * 1024 + h * 64 + lg * 4;
#pragma unroll
    for (int df = 0; df < 4; ++df) {
      ushort4 v;
      v.x = f2bf(o[df][0] * inv);
      v.y = f2bf(o[df][1] * inv);
      v.z = f2bf(o[df][2] * inv);
      v.w = f2bf(o[df][3] * inv);
      *(ushort4*)(yp + df * 16) = v;
    }
  };

  // heavy segment then light segment; every block: 33 kv-tile iterations total
  stage(0, 0);
  __syncthreads();
  run_qtile(31 - pr);
  stage(0, 0);
  __syncthreads();
  run_qtile(pr);
}

// ---------------- launch ----------------
extern "C" void kernel_launch(void* const* d_in, const int* in_sizes, int n_in,
                              void* d_out, int out_size, void* d_ws, size_t ws_size,
                              hipStream_t stream) {
  const float* x = (const float*)d_in[0];
  const float* Wqkv = (const float*)d_in[1];
  const float* Wproj = (const float*)d_in[2];
  const float* qw = (const float*)d_in[3];
  const float* kw = (const float*)d_in[4];
  float* out = (float*)d_out;

  char* ws = (char*)d_ws;
  unsigned short* xb = (unsigned short*)ws;        ws += (size_t)8192 * 1024 * 2;
  unsigned short* wqkvt = (unsigned short*)ws;     ws += (size_t)3072 * 1024 * 2;
  unsigned short* wprojt = (unsigned short*)ws;    ws += (size_t)1024 * 1024 * 2;
  unsigned short* qkvb = (unsigned short*)ws;      ws += (size_t)8192 * 3072 * 2;
  unsigned short* Qr = (unsigned short*)ws;        ws += (size_t)64 * 2048 * 64 * 2;
  unsigned short* Kr = (unsigned short*)ws;        ws += (size_t)64 * 2048 * 64 * 2;
  unsigned short* Vtg = (unsigned short*)ws;       ws += (size_t)64 * 64 * 2048 * 2;
  unsigned short* yb = (unsigned short*)ws;        ws += (size_t)8192 * 1024 * 2;
  float* cosT = (float*)ws;                        ws += (size_t)2048 * 32 * 4;
  float* sinT = (float*)ws;                        ws += (size_t)2048 * 32 * 4;

  cvt_f32_bf16<<<2048, 256, 0, stream>>>(x, xb, 8192 * 1024 / 4);
  transpose_f32_bf16<<<dim3(48, 16), 256, 0, stream>>>(Wqkv, wqkvt, 1024, 3072);
  transpose_f32_bf16<<<dim3(16, 16), 256, 0, stream>>>(Wproj, wprojt, 1024, 1024);
  rope_tab<<<256, 256, 0, stream>>>(cosT, sinT);
  gemm_ring<unsigned short><<<dim3(24, 64), 256, 0, stream>>>(xb, wqkvt, qkvb, 8192, 3072, 1024);
  qkv_post<<<8192, 256, 0, stream>>>(qkvb, qw, kw, cosT, sinT, Qr, Kr);
  vtrans<<<dim3(32, 64), 256, 0, stream>>>(qkvb, Vtg);
  attn_fwd<<<dim3(64, 16), 256, 0, stream>>>(Qr, Kr, Vtg, yb);
  gemm_ring<float><<<dim3(8, 64), 256, 0, stream>>>(yb, wprojt, out, 8192, 1024, 1024);
}

// Round 10
// 200.690 us; speedup vs baseline: 1.1640x; 1.0407x over previous
//
#include <hip/hip_runtime.h>
#include <cstdint>
#include <type_traits>

// ---------------- common types / helpers ----------------
typedef __attribute__((ext_vector_type(8))) short bf16x8;   // 8 bf16 in 4 VGPRs
typedef __attribute__((ext_vector_type(4))) float f32x4;

typedef unsigned int __attribute__((address_space(1))) as1_uint;
typedef unsigned int __attribute__((address_space(3))) as3_uint;

__device__ __forceinline__ void llds16(const void* g, void* l) {
  // async global->LDS, 16B per lane; LDS dst is wave-uniform base + lane*16
  __builtin_amdgcn_global_load_lds((const as1_uint*)g, (as3_uint*)l, 16, 0, 0);
}

__device__ __forceinline__ unsigned short f2bf(float f) {
  unsigned int u = __builtin_bit_cast(unsigned int, f);
  u = (u + 0x7fffu + ((u >> 16) & 1u)) >> 16;   // RNE
  return (unsigned short)u;
}
__device__ __forceinline__ float bf2f(unsigned short h) {
  unsigned int u = ((unsigned int)h) << 16;
  return __builtin_bit_cast(float, u);
}

// ---------------- elementwise convert f32 -> bf16 ----------------
__global__ __launch_bounds__(256) void cvt_f32_bf16(const float* __restrict__ in,
                                                    unsigned short* __restrict__ out, int n4) {
  int i = blockIdx.x * blockDim.x + threadIdx.x;
  int stride = gridDim.x * blockDim.x;
  for (; i < n4; i += stride) {
    float4 v = ((const float4*)in)[i];
    uint2 p;
    p.x = (unsigned)f2bf(v.x) | ((unsigned)f2bf(v.y) << 16);
    p.y = (unsigned)f2bf(v.z) | ((unsigned)f2bf(v.w) << 16);
    ((uint2*)out)[i] = p;
  }
}

// ---------------- transpose + convert: W[K][N] f32 -> Wt[N][K] bf16 ----------------
__global__ __launch_bounds__(256) void transpose_f32_bf16(const float* __restrict__ W,
                                                          unsigned short* __restrict__ Wt,
                                                          int K, int N) {
  __shared__ float tile[64][65];
  int n0 = blockIdx.x * 64, k0 = blockIdx.y * 64;
  int t = threadIdx.x;
  int lr = t >> 4, lc = (t & 15) * 4;
#pragma unroll
  for (int i = 0; i < 4; ++i) {
    int k = lr + i * 16;
    float4 v = *(const float4*)&W[(size_t)(k0 + k) * N + n0 + lc];
    tile[k][lc] = v.x; tile[k][lc + 1] = v.y; tile[k][lc + 2] = v.z; tile[k][lc + 3] = v.w;
  }
  __syncthreads();
  int n = t >> 2, kc = (t & 3) * 16;
  unsigned short* dst = &Wt[(size_t)(n0 + n) * K + k0 + kc];
#pragma unroll
  for (int j = 0; j < 16; ++j) dst[j] = f2bf(tile[kc + j][n]);
}

// ---------------- RoPE tables (TRANSPOSED): cos/sin [32][2048] ----------------
__global__ __launch_bounds__(256) void rope_tabT(float* __restrict__ cosT, float* __restrict__ sinT) {
  int i = blockIdx.x * 256 + threadIdx.x;  // < 32*2048
  int dm = i >> 11, t = i & 2047;
  float inv = powf(10000.0f, -(float)dm * (1.0f / 32.0f));
  float a = (float)t * inv;
  cosT[i] = cosf(a);
  sinT[i] = sinf(a);
}

// ---------------- ring-3 NT GEMM (proj): C[M][N] = A[M][K] * Bt[N][K]^T --------------
// vmcnt(4) steady-state; vmcnt(0) on the FINAL iteration (its loads are the
// newest 4 outstanding -- vmcnt(4) would not cover them; this was the R9 race).
template <typename OutT>
__global__ __launch_bounds__(256) void gemm_ring(const unsigned short* __restrict__ A,
                                                 const unsigned short* __restrict__ Bt,
                                                 OutT* __restrict__ C, int M, int N, int K) {
  __shared__ unsigned short As[3][128 * 32];
  __shared__ unsigned short Bs[3][128 * 32];
  const int tid = threadIdx.x;
  const int w = tid >> 6, lane = tid & 63;
  const int l15 = lane & 15, lg = lane >> 4;
  const int wr = w >> 1, wc = w & 1;

  const int nwg = gridDim.x * gridDim.y;
  const int lin = blockIdx.y * gridDim.x + blockIdx.x;
  const int swzb = (lin & 7) * (nwg >> 3) + (lin >> 3);
  const int bx = swzb % gridDim.x, by = swzb / gridDim.x;
  const int m0 = by * 128, n0 = bx * 128;

  const size_t K2 = (size_t)K * 2;
  const char* Ag = (const char*)A;
  const char* Bg = (const char*)Bt;
  const int rc = lane >> 2;            // row within chunk 0..15
  const int cb = (lane & 3) * 16;      // byte col within row

  auto stage = [&](int buf, int kt) {
#pragma unroll
    for (int i = 0; i < 2; ++i) {
      int c = w + i * 4;
      int row = c * 16 + rc;
      int srcc = cb ^ (((row >> 1) & 3) << 4);
      size_t kofs = (size_t)kt * 64 + srcc;
      llds16(Ag + (size_t)(m0 + row) * K2 + kofs, (char*)&As[buf][0] + c * 1024);
      llds16(Bg + (size_t)(n0 + row) * K2 + kofs, (char*)&Bs[buf][0] + c * 1024);
    }
  };

  f32x4 acc[4][4] = {};
  const int nk = K >> 5;
  stage(0, 0);
  stage(1, 1);
  int cur = 0;
  for (int t = 0; t < nk; ++t) {
    if (t + 1 < nk) asm volatile("s_waitcnt vmcnt(4)" ::: "memory");
    else            asm volatile("s_waitcnt vmcnt(0)" ::: "memory");
    __builtin_amdgcn_s_barrier();
    asm volatile("" ::: "memory");
    if (t + 2 < nk) stage(cur + 2 >= 3 ? cur - 1 : cur + 2, t + 2);

    const unsigned short* Ab = &As[cur][0];
    const unsigned short* Bb = &Bs[cur][0];
    bf16x8 af[4], bfr[4];
#pragma unroll
    for (int m = 0; m < 4; ++m) {
      int row = wr * 64 + m * 16 + l15;
      af[m] = *(const bf16x8*)((const char*)Ab + row * 64 + ((lg * 16) ^ (((row >> 1) & 3) << 4)));
    }
#pragma unroll
    for (int n = 0; n < 4; ++n) {
      int row = wc * 64 + n * 16 + l15;
      bfr[n] = *(const bf16x8*)((const char*)Bb + row * 64 + ((lg * 16) ^ (((row >> 1) & 3) << 4)));
    }
#pragma unroll
    for (int m = 0; m < 4; ++m)
#pragma unroll
      for (int n = 0; n < 4; ++n)
        acc[m][n] = __builtin_amdgcn_mfma_f32_16x16x32_bf16(af[m], bfr[n], acc[m][n], 0, 0, 0);
    cur = (cur == 2) ? 0 : cur + 1;
  }

#pragma unroll
  for (int m = 0; m < 4; ++m)
#pragma unroll
    for (int n = 0; n < 4; ++n) {
      int row = m0 + wr * 64 + m * 16 + lg * 4;
      int col = n0 + wc * 64 + n * 16 + l15;
#pragma unroll
      for (int r = 0; r < 4; ++r) {
        if constexpr (std::is_same<OutT, float>::value)
          C[(size_t)(row + r) * N + col] = acc[m][n][r];
        else
          C[(size_t)(row + r) * N + col] = f2bf(acc[m][n][r]);
      }
    }
}

// ---------------- fused QKV GEMM: x @ Wqkv + RMSNorm + RoPE + relayout ----------------
// A: xb [8192][1024] bf16, Bt: wqkvt [3072][1024] bf16.
// Outputs: Qr/Kr [B*H][2048][64] bf16 (Q pre-scaled log2e/8), Vtg [B*H][64][2048] bf16.
// Each wave's 64x64 output tile = 64 rows x ONE full head: RMSNorm = 4 shfl_xor
// within 16 lanes; RoPE pair d<->d+-32 = n<->n+2 in the SAME lane. V third is
// LDS-transposed (reusing staging buffers) and written coalesced to Vtg.
__global__ __launch_bounds__(256) void gemm_qkv(const unsigned short* __restrict__ A,
                                                const unsigned short* __restrict__ Bt,
                                                const float* __restrict__ qw,
                                                const float* __restrict__ kw,
                                                const float* __restrict__ cosTT,
                                                const float* __restrict__ sinTT,
                                                unsigned short* __restrict__ Qr,
                                                unsigned short* __restrict__ Kr,
                                                unsigned short* __restrict__ Vtg) {
  constexpr int K = 1024;
  __shared__ unsigned short smem[6 * 128 * 32];     // As(3) | Bs(3); reused for V transpose
  unsigned short* As = smem;
  unsigned short* Bs = smem + 3 * 128 * 32;

  const int tid = threadIdx.x;
  const int w = tid >> 6, lane = tid & 63;
  const int l15 = lane & 15, lg = lane >> 4;
  const int wr = w >> 1, wc = w & 1;

  const int nwg = gridDim.x * gridDim.y;     // 1536, % 8 == 0
  const int lin = blockIdx.y * gridDim.x + blockIdx.x;
  const int swzb = (lin & 7) * (nwg >> 3) + (lin >> 3);
  const int bx = swzb % gridDim.x, by = swzb / gridDim.x;
  const int m0 = by * 128, n0 = bx * 128;

  const size_t K2 = (size_t)K * 2;
  const char* Ag = (const char*)A;
  const char* Bg = (const char*)Bt;
  const int rc = lane >> 2;
  const int cb = (lane & 3) * 16;

  auto stage = [&](int buf, int kt) {
#pragma unroll
    for (int i = 0; i < 2; ++i) {
      int c = w + i * 4;
      int row = c * 16 + rc;
      int srcc = cb ^ (((row >> 1) & 3) << 4);
      size_t kofs = (size_t)kt * 64 + srcc;
      llds16(Ag + (size_t)(m0 + row) * K2 + kofs, (char*)As + buf * 8192 + c * 1024);
      llds16(Bg + (size_t)(n0 + row) * K2 + kofs, (char*)Bs + buf * 8192 + c * 1024);
    }
  };

  f32x4 acc[4][4] = {};
  const int nk = K >> 5;
  stage(0, 0);
  stage(1, 1);
  int cur = 0;
  for (int t = 0; t < nk; ++t) {
    if (t + 1 < nk) asm volatile("s_waitcnt vmcnt(4)" ::: "memory");
    else            asm volatile("s_waitcnt vmcnt(0)" ::: "memory");
    __builtin_amdgcn_s_barrier();
    asm volatile("" ::: "memory");
    if (t + 2 < nk) stage(cur + 2 >= 3 ? cur - 1 : cur + 2, t + 2);

    const char* Ab = (const char*)As + cur * 8192;
    const char* Bb = (const char*)Bs + cur * 8192;
    bf16x8 af[4], bfr[4];
#pragma unroll
    for (int m = 0; m < 4; ++m) {
      int row = wr * 64 + m * 16 + l15;
      af[m] = *(const bf16x8*)(Ab + row * 64 + ((lg * 16) ^ (((row >> 1) & 3) << 4)));
    }
#pragma unroll
    for (int n = 0; n < 4; ++n) {
      int row = wc * 64 + n * 16 + l15;
      bfr[n] = *(const bf16x8*)(Bb + row * 64 + ((lg * 16) ^ (((row >> 1) & 3) << 4)));
    }
#pragma unroll
    for (int m = 0; m < 4; ++m)
#pragma unroll
      for (int n = 0; n < 4; ++n)
        acc[m][n] = __builtin_amdgcn_mfma_f32_16x16x32_bf16(af[m], bfr[n], acc[m][n], 0, 0, 0);
    cur = (cur == 2) ? 0 : cur + 1;
  }

  // ---- fused epilogue ----
  const int cls = bx >> 3;                 // 0=Q, 1=K, 2=V third (N=3072, 128 cols/block)
  const int head = (bx & 7) * 2 + wc;      // this wave's head (64 cols = 1 head)
  const int rowb = m0 + wr * 64;           // wave's first global row
  const int b = rowb >> 11;
  const int tl = rowb & 2047;              // t of wave's row 0 (multiple of 64)
  const int bh = b * 16 + head;

  if (cls < 2) {
    const float* wt = cls ? kw : qw;
    const float scale = cls ? 1.0f : 0.18033688011112042f;   // log2(e)/8 folded into Q
    unsigned short* outp = cls ? Kr : Qr;
    float wv[4];
#pragma unroll
    for (int n = 0; n < 4; ++n) wv[n] = wt[n * 16 + l15];
    const float* c0p = cosTT + l15 * 2048;
    const float* c1p = cosTT + (16 + l15) * 2048;
    const float* s0p = sinTT + l15 * 2048;
    const float* s1p = sinTT + (16 + l15) * 2048;
#pragma unroll
    for (int m = 0; m < 4; ++m) {
      int t0 = tl + m * 16 + lg * 4;
      f32x4 ssq = {};
#pragma unroll
      for (int n = 0; n < 4; ++n) ssq += acc[m][n] * acc[m][n];
#pragma unroll
      for (int r = 0; r < 4; ++r) {
        float v = ssq[r];
        v += __shfl_xor(v, 1); v += __shfl_xor(v, 2);
        v += __shfl_xor(v, 4); v += __shfl_xor(v, 8);
        ssq[r] = rsqrtf(v * (1.0f / 64.0f) + 1e-5f) * scale;
      }
      f32x4 nv[4];
#pragma unroll
      for (int n = 0; n < 4; ++n) nv[n] = acc[m][n] * ssq * wv[n];
      f32x4 cv0 = *(const f32x4*)(c0p + t0);
      f32x4 cv1 = *(const f32x4*)(c1p + t0);
      f32x4 sv0 = *(const f32x4*)(s0p + t0);
      f32x4 sv1 = *(const f32x4*)(s1p + t0);
      f32x4 ov[4];
      ov[0] = nv[0] * cv0 - nv[2] * sv0;
      ov[1] = nv[1] * cv1 - nv[3] * sv1;
      ov[2] = nv[2] * cv0 + nv[0] * sv0;
      ov[3] = nv[3] * cv1 + nv[1] * sv1;
      unsigned short* yp = outp + ((size_t)bh * 2048 + t0) * 64 + l15;
#pragma unroll
      for (int n = 0; n < 4; ++n)
#pragma unroll
        for (int r = 0; r < 4; ++r)
          yp[(size_t)r * 64 + n * 16] = f2bf(ov[n][r]);
    }
  } else {
    // V third: transpose 64t x 64d per wave via LDS, write Vtg[bh][d][t] coalesced
    __syncthreads();                        // all waves done reading As/Bs
    unsigned short* tb = smem + w * (64 * 72);   // per-wave 9216 B region
#pragma unroll
    for (int m = 0; m < 4; ++m)
#pragma unroll
      for (int n = 0; n < 4; ++n) {
        int d = n * 16 + l15, t = m * 16 + lg * 4;
        ushort4 pk;
        pk.x = f2bf(acc[m][n][0]); pk.y = f2bf(acc[m][n][1]);
        pk.z = f2bf(acc[m][n][2]); pk.w = f2bf(acc[m][n][3]);
        *(ushort4*)(tb + d * 72 + t) = pk;
      }
    asm volatile("" ::: "memory");          // per-wave LDS in-order: writes before reads
    int d2 = lane;
    unsigned short* vp = Vtg + ((size_t)bh * 64 + d2) * 2048 + tl;
#pragma unroll
    for (int j = 0; j < 8; ++j) {
      bf16x8 vv = *(const bf16x8*)(tb + d2 * 72 + j * 8);
      *(bf16x8*)(vp + j * 8) = vv;
    }
  }
}

// ---------------- causal flash attention: swapped operands, fixed-max softmax ----------
// Q,K: [B*H][T][64] bf16 (Q pre-scaled by log2e/8). Vtg: [B*H][64][T] bf16.
// Y: [B][T][H*64] bf16.
// Swapped-operand trick: mfma(Kfrag, Qfrag) -> S^T, mfma(Vtfrag, Pfrag) -> O^T.
// Each lane owns one q column: scalar psum, packed P stores, vector Y stores.
// QBLK=64 (4 waves x 16 q), KVBLK=64, paired q-tiles {31-p, p} -> uniform load.
__global__ __launch_bounds__(256) void attn_fwd(const unsigned short* __restrict__ Q,
                                                const unsigned short* __restrict__ K,
                                                const unsigned short* __restrict__ Vtg,
                                                unsigned short* __restrict__ Y) {
  const int bh = blockIdx.x;        // 0..63
  const int pr = blockIdx.y;        // 0..15
  const int b = bh >> 4, h = bh & 15;
  const int tid = threadIdx.x;
  const int w = tid >> 6, lane = tid & 63;
  const int l15 = lane & 15, lg = lane >> 4;

  __shared__ unsigned short Kl[2][64 * 64];   // swizzled [k][d], 128B rows (16384 B)
  __shared__ unsigned short Vt[2][64 * 64];   // swizzled [d][k], 128B rows (16384 B)
  __shared__ unsigned short Pl[4][16 * 64];   // per-wave P^T [q][k], 128B rows, swz (8192 B)

  const size_t bhT = (size_t)bh * 2048;
  const char* Kg = (const char*)(K + bhT * 64);          // row stride 128B
  const char* Vg = (const char*)(Vtg + bhT * 64);        // row stride 4096B

  auto stage = [&](int buf, int kt) {
#pragma unroll
    for (int i = 0; i < 2; ++i) {
      int c = w * 2 + i;                     // chunk 0..7, wave-uniform
      int pos = c * 1024 + lane * 16;        // linear byte in 8KB tile
      int row = pos >> 7, cb = pos & 127;
      int srcb = cb ^ ((row & 7) << 4);      // inverse-swizzled source
      llds16(Kg + ((size_t)(kt * 64 + row)) * 128 + srcb,
             (char*)&Kl[buf][0] + c * 1024);
      llds16(Vg + (size_t)row * 4096 + (size_t)kt * 128 + srcb,
             (char*)&Vt[buf][0] + c * 1024);
    }
  };

  auto run_qtile = [&](int qtb) {
    const int qbase = qtb * 64;
    const unsigned short* Qp = Q + (bhT + qbase + w * 16 + l15) * 64 + lg * 8;
    bf16x8 aq[2];
    aq[0] = *(const bf16x8*)(Qp);
    aq[1] = *(const bf16x8*)(Qp + 32);

    f32x4 o[4] = {};        // O^T: lane q=l15, rows d = df*16 + lg*4 + r
    float psum = 0.0f;      // per-lane (q = l15) partial sum over its k slice

    char* Pw = (char*)&Pl[w][0];
    const int psw = (l15 & 7) << 4;       // 16B-granular XOR swizzle keyed by q-row

    for (int kt = 0; kt <= qtb; ++kt) {
      const int cur = kt & 1;
      if (kt < qtb) stage(cur ^ 1, kt + 1);
      const char* Kc = (const char*)&Kl[cur][0];
      const char* Vc = (const char*)&Vt[cur][0];

      f32x4 s[4] = {};      // S^T: lane q=l15, rows k = n*16 + lg*4 + r
      __builtin_amdgcn_s_setprio(1);
#pragma unroll
      for (int n = 0; n < 4; ++n) {
        int r = n * 16 + l15, sw = (r & 7) << 4;
#pragma unroll
        for (int ks = 0; ks < 2; ++ks) {
          bf16x8 bk = *(const bf16x8*)(Kc + r * 128 + ((ks * 64 + lg * 16) ^ sw));
          s[n] = __builtin_amdgcn_mfma_f32_16x16x32_bf16(bk, aq[ks], s[n], 0, 0, 0);
        }
      }
      __builtin_amdgcn_s_setprio(0);

      if (kt == qtb) {   // diagonal tile: causal mask (k_local > q_local)
#pragma unroll
        for (int n = 0; n < 4; ++n)
#pragma unroll
          for (int r = 0; r < 4; ++r)
            if (n * 16 + lg * 4 + r > w * 16 + l15) s[n][r] = -1e30f;
      }

      // p = exp2(s); per-lane psum; pack 4 k-contiguous bf16 -> one b64 LDS write
#pragma unroll
      for (int n = 0; n < 4; ++n) {
        float p0 = __builtin_exp2f(s[n][0]);
        float p1 = __builtin_exp2f(s[n][1]);
        float p2 = __builtin_exp2f(s[n][2]);
        float p3 = __builtin_exp2f(s[n][3]);
        psum += (p0 + p1) + (p2 + p3);
        uint2 pk;
        pk.x = ((__builtin_bit_cast(unsigned int, p0) + 0x8000u) >> 16) |
               (((__builtin_bit_cast(unsigned int, p1) + 0x8000u) >> 16) << 16);
        pk.y = ((__builtin_bit_cast(unsigned int, p2) + 0x8000u) >> 16) |
               (((__builtin_bit_cast(unsigned int, p3) + 0x8000u) >> 16) << 16);
        *(uint2*)(Pw + l15 * 128 + ((n * 32 + lg * 8) ^ psw)) = pk;
      }
      asm volatile("" ::: "memory");  // keep P stores before P reads (per-wave LDS in-order)

      bf16x8 ap[2];
      ap[0] = *(const bf16x8*)(Pw + l15 * 128 + ((lg * 16) ^ psw));
      ap[1] = *(const bf16x8*)(Pw + l15 * 128 + ((64 + lg * 16) ^ psw));

      __builtin_amdgcn_s_setprio(1);
#pragma unroll
      for (int df = 0; df < 4; ++df) {
        int rr = df * 16 + l15, sw = (rr & 7) << 4;
#pragma unroll
        for (int ks = 0; ks < 2; ++ks) {
          bf16x8 bv = *(const bf16x8*)(Vc + rr * 128 + ((ks * 64 + lg * 16) ^ sw));
          o[df] = __builtin_amdgcn_mfma_f32_16x16x32_bf16(bv, ap[ks], o[df], 0, 0, 0);
        }
      }
      __builtin_amdgcn_s_setprio(0);
      __syncthreads();  // drains next-tile staging; protects cur from overwrite
    }

    // full row-sum: combine the 4 lanes sharing this q (lg differs in bits 4..5)
    psum += __shfl_xor(psum, 16);
    psum += __shfl_xor(psum, 32);
    float inv = 1.0f / psum;

    size_t q = qbase + w * 16 + l15;
    unsigned short* yp = Y + ((size_t)b * 2048 + q) * 1024 + h * 64 + lg * 4;
#pragma unroll
    for (int df = 0; df < 4; ++df) {
      ushort4 v;
      v.x = f2bf(o[df][0] * inv);
      v.y = f2bf(o[df][1] * inv);
      v.z = f2bf(o[df][2] * inv);
      v.w = f2bf(o[df][3] * inv);
      *(ushort4*)(yp + df * 16) = v;
    }
  };

  // heavy segment then light segment; every block: 33 kv-tile iterations total
  stage(0, 0);
  __syncthreads();
  run_qtile(31 - pr);
  stage(0, 0);
  __syncthreads();
  run_qtile(pr);
}

// ---------------- launch ----------------
extern "C" void kernel_launch(void* const* d_in, const int* in_sizes, int n_in,
                              void* d_out, int out_size, void* d_ws, size_t ws_size,
                              hipStream_t stream) {
  const float* x = (const float*)d_in[0];
  const float* Wqkv = (const float*)d_in[1];
  const float* Wproj = (const float*)d_in[2];
  const float* qw = (const float*)d_in[3];
  const float* kw = (const float*)d_in[4];
  float* out = (float*)d_out;

  char* ws = (char*)d_ws;
  unsigned short* xb = (unsigned short*)ws;        ws += (size_t)8192 * 1024 * 2;
  unsigned short* wqkvt = (unsigned short*)ws;     ws += (size_t)3072 * 1024 * 2;
  unsigned short* wprojt = (unsigned short*)ws;    ws += (size_t)1024 * 1024 * 2;
  unsigned short* Qr = (unsigned short*)ws;        ws += (size_t)64 * 2048 * 64 * 2;
  unsigned short* Kr = (unsigned short*)ws;        ws += (size_t)64 * 2048 * 64 * 2;
  unsigned short* Vtg = (unsigned short*)ws;       ws += (size_t)64 * 64 * 2048 * 2;
  unsigned short* yb = (unsigned short*)ws;        ws += (size_t)8192 * 1024 * 2;
  float* cosTT = (float*)ws;                       ws += (size_t)32 * 2048 * 4;
  float* sinTT = (float*)ws;                       ws += (size_t)32 * 2048 * 4;

  cvt_f32_bf16<<<2048, 256, 0, stream>>>(x, xb, 8192 * 1024 / 4);
  transpose_f32_bf16<<<dim3(48, 16), 256, 0, stream>>>(Wqkv, wqkvt, 1024, 3072);
  transpose_f32_bf16<<<dim3(16, 16), 256, 0, stream>>>(Wproj, wprojt, 1024, 1024);
  rope_tabT<<<256, 256, 0, stream>>>(cosTT, sinTT);
  gemm_qkv<<<dim3(24, 64), 256, 0, stream>>>(xb, wqkvt, qw, kw, cosTT, sinTT, Qr, Kr, Vtg);
  attn_fwd<<<dim3(64, 16), 256, 0, stream>>>(Qr, Kr, Vtg, yb);
  gemm_ring<float><<<dim3(8, 64), 256, 0, stream>>>(yb, wprojt, out, 8192, 1024, 1024);
}